// Round 1
// baseline (541.200 us; speedup 1.0000x reference)
//
#include <hip/hip_runtime.h>

typedef __bf16 bf16;
typedef __bf16 bf16x8 __attribute__((ext_vector_type(8)));
typedef __bf16 bf16x4 __attribute__((ext_vector_type(4)));
typedef float  f32x4  __attribute__((ext_vector_type(4)));

// Problem constants (from reference): FX=64, FU=64, f_in=192, H=256, FE_OUT=64
#define KDIM 192
#define HDIM 256
#define NOUT 64

// ---------------------------------------------------------------------------
// Prep: transpose + convert weights to bf16 [N][K] row-major so that MFMA
// B-fragment loads (lane reads 8 contiguous K elements for fixed n=lane&15)
// are 16B contiguous loads.
//   W1 [192][256] fp32  -> W1T [256][192] bf16
//   W2 [256][64]  fp32  -> W2T [64][256]  bf16
// ---------------------------------------------------------------------------
__global__ __launch_bounds__(256) void prep_weights(
    const float* __restrict__ W1, const float* __restrict__ W2,
    bf16* __restrict__ W1T, bf16* __restrict__ W2T)
{
    int gid = blockIdx.x * 256 + threadIdx.x;
    if (gid < KDIM * HDIM) {               // 49152
        int k = gid >> 8;                  // 0..191
        int n = gid & 255;                 // 0..255
        W1T[n * KDIM + k] = (bf16)W1[gid]; // read coalesced, write strided (tiny, one-shot)
    } else {
        int g2 = gid - KDIM * HDIM;        // 0..16383
        int k = g2 >> 6;                   // 0..255
        int n = g2 & 63;                   // 0..63
        W2T[n * HDIM + k] = (bf16)W2[g2];
    }
}

// ---------------------------------------------------------------------------
// Fused edge MLP: per block, 64 edges.
//   xs[64][192] bf16 = [dest | src | u[batch]]   (LDS, +8 pad -> 400B stride)
//   layer1: [64,192]@[192,256] via 16x16x32 bf16 MFMA, wave w owns N cols [64w,64w+64)
//   h = relu(. + b1) -> hs[64][256] bf16 (LDS, +8 pad)
//   layer2: [64,256]@[256,64], wave w owns rows [16w,16w+16)
//   out fp32 + b2
// ---------------------------------------------------------------------------
__global__ __launch_bounds__(256, 2) void edge_mlp(
    const float* __restrict__ srcf, const float* __restrict__ destf,
    const float* __restrict__ u,    const int* __restrict__ batch,
    const bf16* __restrict__ W1T,   const float* __restrict__ b1,
    const bf16* __restrict__ W2T,   const float* __restrict__ b2,
    float* __restrict__ out, int E)
{
    __shared__ bf16 xs[64][200];   // 192 + 8 pad  -> 400 B row stride (16B-mult)
    __shared__ bf16 hs[64][264];   // 256 + 8 pad  -> 528 B row stride (16B-mult)

    const int tid = threadIdx.x;
    const int e0  = blockIdx.x * 64;

    // ---- stage x tile: 4 threads per edge row, 16 floats each per segment ----
    {
        const int row  = tid >> 2;        // 0..63
        const int part = tid & 3;         // 0..3
        const int c0   = part * 16;
        const int e    = e0 + row;
        if (e < E) {
            const int b = batch[e];
            const float* dp = destf + (size_t)e * 64 + c0;
            const float* sp = srcf  + (size_t)e * 64 + c0;
            const float* up = u     + (size_t)b * 64 + c0;
#pragma unroll
            for (int i = 0; i < 4; ++i) {
                float4 d4 = *(const float4*)(dp + i * 4);
                float4 s4 = *(const float4*)(sp + i * 4);
                float4 u4 = *(const float4*)(up + i * 4);
                bf16x4 db = { (bf16)d4.x, (bf16)d4.y, (bf16)d4.z, (bf16)d4.w };
                bf16x4 sb = { (bf16)s4.x, (bf16)s4.y, (bf16)s4.z, (bf16)s4.w };
                bf16x4 ub = { (bf16)u4.x, (bf16)u4.y, (bf16)u4.z, (bf16)u4.w };
                *(bf16x4*)&xs[row][c0 + i * 4]       = db;
                *(bf16x4*)&xs[row][64 + c0 + i * 4]  = sb;
                *(bf16x4*)&xs[row][128 + c0 + i * 4] = ub;
            }
        } else {
            bf16x4 z = { (bf16)0.f, (bf16)0.f, (bf16)0.f, (bf16)0.f };
#pragma unroll
            for (int i = 0; i < 4; ++i) {
                *(bf16x4*)&xs[row][c0 + i * 4]       = z;
                *(bf16x4*)&xs[row][64 + c0 + i * 4]  = z;
                *(bf16x4*)&xs[row][128 + c0 + i * 4] = z;
            }
        }
    }
    __syncthreads();

    const int wave = tid >> 6;
    const int lane = tid & 63;
    const int q    = lane >> 4;   // quad 0..3
    const int cl   = lane & 15;   // 0..15

    // ---- layer 1: wave owns N cols [wn0, wn0+64), all 64 M rows ----
    const int wn0 = wave * 64;
    f32x4 acc[4][4] = {};   // [mt][nt]

    const bf16* w1base = W1T + (size_t)wn0 * KDIM;
#pragma unroll
    for (int ks = 0; ks < 6; ++ks) {
        const int k0 = ks * 32 + q * 8;
        bf16x8 a[4], b[4];
#pragma unroll
        for (int mt = 0; mt < 4; ++mt)
            a[mt] = *(const bf16x8*)&xs[mt * 16 + cl][k0];
#pragma unroll
        for (int nt = 0; nt < 4; ++nt)
            b[nt] = *(const bf16x8*)(w1base + (size_t)(nt * 16 + cl) * KDIM + k0);
#pragma unroll
        for (int mt = 0; mt < 4; ++mt)
#pragma unroll
            for (int nt = 0; nt < 4; ++nt)
                acc[mt][nt] = __builtin_amdgcn_mfma_f32_16x16x32_bf16(
                    a[mt], b[nt], acc[mt][nt], 0, 0, 0);
    }

    // ---- epilogue 1: + b1, relu, bf16 -> hs ----
#pragma unroll
    for (int nt = 0; nt < 4; ++nt) {
        const float bias = b1[wn0 + nt * 16 + cl];
#pragma unroll
        for (int mt = 0; mt < 4; ++mt) {
#pragma unroll
            for (int r = 0; r < 4; ++r) {
                float v = acc[mt][nt][r] + bias;
                v = v > 0.f ? v : 0.f;
                hs[mt * 16 + q * 4 + r][wn0 + nt * 16 + cl] = (bf16)v;
            }
        }
    }
    __syncthreads();

    // ---- layer 2: wave owns M rows [16w, 16w+16), all 64 N cols, K=256 ----
    const int m0 = wave * 16;
    f32x4 acc2[4] = {};   // [nt]
#pragma unroll
    for (int ks = 0; ks < 8; ++ks) {
        const int k0 = ks * 32 + q * 8;
        bf16x8 a = *(const bf16x8*)&hs[m0 + cl][k0];
#pragma unroll
        for (int nt = 0; nt < 4; ++nt) {
            bf16x8 b = *(const bf16x8*)(W2T + (size_t)(nt * 16 + cl) * HDIM + k0);
            acc2[nt] = __builtin_amdgcn_mfma_f32_16x16x32_bf16(a, b, acc2[nt], 0, 0, 0);
        }
    }

    // ---- epilogue 2: + b2, store fp32 ----
#pragma unroll
    for (int nt = 0; nt < 4; ++nt) {
        const float bias = b2[nt * 16 + cl];
#pragma unroll
        for (int r = 0; r < 4; ++r) {
            const int row = m0 + q * 4 + r;
            const int e   = e0 + row;
            if (e < E)
                out[(size_t)e * 64 + nt * 16 + cl] = acc2[nt][r] + bias;
        }
    }
}

extern "C" void kernel_launch(void* const* d_in, const int* in_sizes, int n_in,
                              void* d_out, int out_size, void* d_ws, size_t ws_size,
                              hipStream_t stream)
{
    const float* srcf  = (const float*)d_in[0];
    const float* destf = (const float*)d_in[1];
    // d_in[2] = edge_attr: UNUSED by reference — never touched.
    const float* u     = (const float*)d_in[3];
    const int*   batch = (const int*)d_in[4];
    const float* W1    = (const float*)d_in[5];
    const float* b1    = (const float*)d_in[6];
    const float* W2    = (const float*)d_in[7];
    const float* b2    = (const float*)d_in[8];
    float* out = (float*)d_out;

    const int E = in_sizes[0] / 64;   // src is [E, 64]

    bf16* W1T = (bf16*)d_ws;                  // 256*192 bf16 = 98304 B
    bf16* W2T = W1T + KDIM * HDIM;            // 64*256  bf16 = 32768 B

    prep_weights<<<(KDIM * HDIM + HDIM * NOUT) / 256, 256, 0, stream>>>(W1, W2, W1T, W2T);

    const int nblocks = (E + 63) / 64;
    edge_mlp<<<nblocks, 256, 0, stream>>>(srcf, destf, u, batch,
                                          W1T, b1, W2T, b2, out, E);
}

// Round 2
// 528.109 us; speedup vs baseline: 1.0248x; 1.0248x over previous
//
#include <hip/hip_runtime.h>

typedef __bf16 bf16;
typedef __bf16 bf16x8 __attribute__((ext_vector_type(8)));
typedef __bf16 bf16x4 __attribute__((ext_vector_type(4)));
typedef float  f32x4  __attribute__((ext_vector_type(4)));

// Problem constants: FX=64, FU=64, f_in=192, H=256, FE_OUT=64
#define KDIM 192
#define HDIM 256
#define NOUT 64

// ---------------------------------------------------------------------------
// Prep: W1 [192][256] fp32 -> W1T [256][192] bf16 ; W2 [256][64] -> W2T [64][256]
// Coalesced WRITES (consecutive gid -> consecutive W*T addr); strided reads hit L2.
// ---------------------------------------------------------------------------
__global__ __launch_bounds__(256) void prep_weights(
    const float* __restrict__ W1, const float* __restrict__ W2,
    bf16* __restrict__ W1T, bf16* __restrict__ W2T)
{
    int gid = blockIdx.x * 256 + threadIdx.x;
    if (gid < KDIM * HDIM) {                  // 49152 = W1T elements
        int n = gid / KDIM;                   // 0..255
        int k = gid - n * KDIM;               // 0..191
        W1T[gid] = (bf16)W1[k * HDIM + n];
    } else {
        int g2 = gid - KDIM * HDIM;           // 0..16383
        int n = g2 >> 8;                      // 0..63
        int k = g2 & 255;                     // 0..255
        W2T[g2] = (bf16)W2[k * NOUT + n];
    }
}

// ---------------------------------------------------------------------------
// Fused edge MLP, software-pipelined over 64-edge tiles (grid-stride).
// Per tile: xs[64][192]bf16 = [dest|src|u[batch]] in LDS; layer1 via 16x16x32
// bf16 MFMA (wave owns 64 N-cols); relu+b1 -> hs LDS; layer2 (wave owns 16
// M-rows); +b2 fp32 store. Next tile's global loads are issued into registers
// before the first barrier so HBM latency hides behind both MFMA phases.
// batch[] is prefetched TWO tiles ahead so the u-gather never waits on it.
// ---------------------------------------------------------------------------
__global__ __launch_bounds__(256, 2) void edge_mlp(
    const float* __restrict__ srcf, const float* __restrict__ destf,
    const float* __restrict__ u,    const int* __restrict__ batch,
    const bf16* __restrict__ W1T,   const float* __restrict__ b1,
    const bf16* __restrict__ W2T,   const float* __restrict__ b2,
    float* __restrict__ out, int E)
{
    __shared__ bf16 xs[64][200];   // 192 + 8 pad
    __shared__ bf16 hs[64][264];   // 256 + 8 pad

    const int tid  = threadIdx.x;
    const int row  = tid >> 2;        // 0..63  (staging row)
    const int c0   = (tid & 3) * 16;  // 0..48  (staging col base)
    const int wave = tid >> 6;
    const int lane = tid & 63;
    const int q    = lane >> 4;       // quad 0..3
    const int cl   = lane & 15;       // 0..15

    const int ntiles = (E + 63) >> 6;
    const int stride = gridDim.x;

    int it = blockIdx.x;
    if (it >= ntiles) return;

    float4 dr[4], sr[4], ur[4];

    // ---- preamble: batch(it) -> x(it) regs ; batch(it+stride) ----
    int e = it * 64 + row;
    int b = (e < E) ? batch[e] : 0;
    if (e < E) {
        const float* dp = destf + (size_t)e * 64 + c0;
        const float* sp = srcf  + (size_t)e * 64 + c0;
        const float* up = u     + (size_t)b * 64 + c0;
#pragma unroll
        for (int i = 0; i < 4; ++i) {
            dr[i] = *(const float4*)(dp + i * 4);
            sr[i] = *(const float4*)(sp + i * 4);
            ur[i] = *(const float4*)(up + i * 4);
        }
    } else {
#pragma unroll
        for (int i = 0; i < 4; ++i) {
            dr[i] = make_float4(0.f, 0.f, 0.f, 0.f);
            sr[i] = dr[i]; ur[i] = dr[i];
        }
    }
    int itn = it + stride;
    int bn  = 0;
    if (itn < ntiles) {
        int en = itn * 64 + row;
        if (en < E) bn = batch[en];
    }

    while (true) {
        const int e0 = it * 64;

        // ---- stage xs from regs (convert fp32 -> bf16) ----
#pragma unroll
        for (int i = 0; i < 4; ++i) {
            bf16x4 db = { (bf16)dr[i].x, (bf16)dr[i].y, (bf16)dr[i].z, (bf16)dr[i].w };
            bf16x4 sb = { (bf16)sr[i].x, (bf16)sr[i].y, (bf16)sr[i].z, (bf16)sr[i].w };
            bf16x4 ub = { (bf16)ur[i].x, (bf16)ur[i].y, (bf16)ur[i].z, (bf16)ur[i].w };
            *(bf16x4*)&xs[row][c0 + i * 4]       = db;
            *(bf16x4*)&xs[row][64 + c0 + i * 4]  = sb;
            *(bf16x4*)&xs[row][128 + c0 + i * 4] = ub;
        }

        // ---- prefetch next tile into regs (issue now, consume next iter) ----
        const bool hasnext = (itn < ntiles);
        float4 dr2[4], sr2[4], ur2[4];
        if (hasnext) {
            int en = itn * 64 + row;
            if (en < E) {
                const float* dp = destf + (size_t)en * 64 + c0;
                const float* sp = srcf  + (size_t)en * 64 + c0;
                const float* up = u     + (size_t)bn * 64 + c0;
#pragma unroll
                for (int i = 0; i < 4; ++i) {
                    dr2[i] = *(const float4*)(dp + i * 4);
                    sr2[i] = *(const float4*)(sp + i * 4);
                    ur2[i] = *(const float4*)(up + i * 4);
                }
            } else {
#pragma unroll
                for (int i = 0; i < 4; ++i) {
                    dr2[i] = make_float4(0.f, 0.f, 0.f, 0.f);
                    sr2[i] = dr2[i]; ur2[i] = dr2[i];
                }
            }
        }
        int itnn = itn + stride;
        int bnn  = 0;
        if (itnn < ntiles) {
            int enn = itnn * 64 + row;
            if (enn < E) bnn = batch[enn];
        }

        __syncthreads();   // xs ready

        // ---- layer 1: wave owns N cols [64w, 64w+64), all 64 M rows ----
        const int wn0 = wave * 64;
        f32x4 acc[4][4] = {};
        const bf16* w1base = W1T + (size_t)wn0 * KDIM;
#pragma unroll
        for (int ks = 0; ks < 6; ++ks) {
            const int k0 = ks * 32 + q * 8;
            bf16x8 a[4], bb[4];
#pragma unroll
            for (int mt = 0; mt < 4; ++mt)
                a[mt] = *(const bf16x8*)&xs[mt * 16 + cl][k0];
#pragma unroll
            for (int nt = 0; nt < 4; ++nt)
                bb[nt] = *(const bf16x8*)(w1base + (size_t)(nt * 16 + cl) * KDIM + k0);
#pragma unroll
            for (int mt = 0; mt < 4; ++mt)
#pragma unroll
                for (int nt = 0; nt < 4; ++nt)
                    acc[mt][nt] = __builtin_amdgcn_mfma_f32_16x16x32_bf16(
                        a[mt], bb[nt], acc[mt][nt], 0, 0, 0);
        }

        // ---- epilogue 1: +b1, relu, bf16 -> hs ----
#pragma unroll
        for (int nt = 0; nt < 4; ++nt) {
            const float bias = b1[wn0 + nt * 16 + cl];
#pragma unroll
            for (int mt = 0; mt < 4; ++mt) {
#pragma unroll
                for (int r = 0; r < 4; ++r) {
                    float v = acc[mt][nt][r] + bias;
                    v = v > 0.f ? v : 0.f;
                    hs[mt * 16 + q * 4 + r][wn0 + nt * 16 + cl] = (bf16)v;
                }
            }
        }
        __syncthreads();   // hs ready

        // ---- layer 2: wave owns M rows [16w, 16w+16), K=256 ----
        const int m0 = wave * 16;
        f32x4 acc2[4] = {};
#pragma unroll
        for (int ks = 0; ks < 8; ++ks) {
            const int k0 = ks * 32 + q * 8;
            bf16x8 a = *(const bf16x8*)&hs[m0 + cl][k0];
#pragma unroll
            for (int nt = 0; nt < 4; ++nt) {
                bf16x8 bb = *(const bf16x8*)(W2T + (size_t)(nt * 16 + cl) * HDIM + k0);
                acc2[nt] = __builtin_amdgcn_mfma_f32_16x16x32_bf16(a, bb, acc2[nt], 0, 0, 0);
            }
        }

        // ---- epilogue 2: +b2, fp32 store ----
#pragma unroll
        for (int nt = 0; nt < 4; ++nt) {
            const float bias = b2[nt * 16 + cl];
#pragma unroll
            for (int r = 0; r < 4; ++r) {
                const int rrow = m0 + q * 4 + r;
                const int ee   = e0 + rrow;
                if (ee < E)
                    out[(size_t)ee * 64 + nt * 16 + cl] = acc2[nt][r] + bias;
            }
        }

        if (!hasnext) break;
        it = itn; itn = itnn; b = bn; bn = bnn;
#pragma unroll
        for (int i = 0; i < 4; ++i) { dr[i] = dr2[i]; sr[i] = sr2[i]; ur[i] = ur2[i]; }
        // NOTE: no barrier needed here — next xs write is ordered after this
        // iteration's hs-ready barrier, and all xs reads completed before it.
    }
}

extern "C" void kernel_launch(void* const* d_in, const int* in_sizes, int n_in,
                              void* d_out, int out_size, void* d_ws, size_t ws_size,
                              hipStream_t stream)
{
    const float* srcf  = (const float*)d_in[0];
    const float* destf = (const float*)d_in[1];
    // d_in[2] = edge_attr: UNUSED by reference — never touched.
    const float* u     = (const float*)d_in[3];
    const int*   batch = (const int*)d_in[4];
    const float* W1    = (const float*)d_in[5];
    const float* b1    = (const float*)d_in[6];
    const float* W2    = (const float*)d_in[7];
    const float* b2    = (const float*)d_in[8];
    float* out = (float*)d_out;

    const int E = in_sizes[0] / 64;   // src is [E, 64]

    bf16* W1T = (bf16*)d_ws;                  // 256*192 bf16 = 98304 B
    bf16* W2T = W1T + KDIM * HDIM;            // 64*256  bf16 = 32768 B

    prep_weights<<<(KDIM * HDIM + HDIM * NOUT) / 256, 256, 0, stream>>>(W1, W2, W1T, W2T);

    const int ntiles = (E + 63) / 64;
    const int nblocks = ntiles < 1024 ? ntiles : 1024;
    edge_mlp<<<nblocks, 256, 0, stream>>>(srcf, destf, u, batch,
                                          W1T, b1, W2T, b2, out, E);
}